// Round 2
// baseline (2686.583 us; speedup 1.0000x reference)
//
#include <hip/hip_runtime.h>
#include <math.h>

#define D_MODEL 1024
#define NUM_HEADS 16
#define HEAD_SIZE 64
#define SEQ 2048
#define BATCH 4
#define M_PROJ (BATCH * SEQ)  // 8192

// ---------------------------------------------------------------------------
// Tiled fp32 GEMM: C[M,N] = A[M,K] @ W[K,N] + bias[N]
// BM=BN=128, BK=16, 256 threads, 2x2 sub-blocks of 4x4 per thread.
// Arithmetic intensity vs LDS: 128 FLOP / 64 B per thread-kstep (2x the 64-tile).
// ---------------------------------------------------------------------------
__global__ __launch_bounds__(256) void gemm_bias_kernel(
    const float* __restrict__ A, const float* __restrict__ W,
    const float* __restrict__ bias, float* __restrict__ C,
    int M, int N, int K) {
  __shared__ float As[16][132];  // [k][m], pad -> bank-friendly
  __shared__ float Ws[16][132];  // [k][n]
  const int tid = threadIdx.x;
  const int bm = blockIdx.y * 128;
  const int bn = blockIdx.x * 128;
  const int tx = tid & 15;  // n
  const int ty = tid >> 4;  // m

  const int ar = tid >> 2;         // A row 0..63 (+64 for 2nd half)
  const int ac = (tid & 3) << 2;   // A k-col 0,4,8,12
  const int wk = tid >> 4;         // W k-row 0..15
  const int wc = (tid & 15) << 2;  // W col 0..60 (+64 for 2nd half)

  float acc[2][2][4][4] = {};

  for (int k0 = 0; k0 < K; k0 += 16) {
#pragma unroll
    for (int h = 0; h < 2; ++h) {
      const int r = ar + h * 64;
      float4 a4 =
          *reinterpret_cast<const float4*>(&A[(size_t)(bm + r) * K + k0 + ac]);
      As[ac + 0][r] = a4.x;
      As[ac + 1][r] = a4.y;
      As[ac + 2][r] = a4.z;
      As[ac + 3][r] = a4.w;
      float4 w4 = *reinterpret_cast<const float4*>(
          &W[(size_t)(k0 + wk) * N + bn + wc + h * 64]);
      *reinterpret_cast<float4*>(&Ws[wk][wc + h * 64]) = w4;
    }
    __syncthreads();
#pragma unroll
    for (int kk = 0; kk < 16; ++kk) {
      float4 a0 = *reinterpret_cast<const float4*>(&As[kk][ty << 2]);
      float4 a1 = *reinterpret_cast<const float4*>(&As[kk][64 + (ty << 2)]);
      float4 w0 = *reinterpret_cast<const float4*>(&Ws[kk][tx << 2]);
      float4 w1 = *reinterpret_cast<const float4*>(&Ws[kk][64 + (tx << 2)]);
      const float am[2][4] = {{a0.x, a0.y, a0.z, a0.w},
                              {a1.x, a1.y, a1.z, a1.w}};
      const float wn[2][4] = {{w0.x, w0.y, w0.z, w0.w},
                              {w1.x, w1.y, w1.z, w1.w}};
#pragma unroll
      for (int p = 0; p < 2; ++p)
#pragma unroll
        for (int q = 0; q < 2; ++q)
#pragma unroll
          for (int i = 0; i < 4; ++i)
#pragma unroll
            for (int j = 0; j < 4; ++j)
              acc[p][q][i][j] += am[p][i] * wn[q][j];
    }
    __syncthreads();
  }

  float4 bv[2];
  bv[0] = *reinterpret_cast<const float4*>(&bias[bn + (tx << 2)]);
  bv[1] = *reinterpret_cast<const float4*>(&bias[bn + 64 + (tx << 2)]);
#pragma unroll
  for (int p = 0; p < 2; ++p)
#pragma unroll
    for (int i = 0; i < 4; ++i) {
      const size_t row = (size_t)(bm + p * 64 + (ty << 2) + i);
#pragma unroll
      for (int q = 0; q < 2; ++q) {
        const float bb[4] = {bv[q].x, bv[q].y, bv[q].z, bv[q].w};
        float4 o;
        o.x = acc[p][q][i][0] + bb[0];
        o.y = acc[p][q][i][1] + bb[1];
        o.z = acc[p][q][i][2] + bb[2];
        o.w = acc[p][q][i][3] + bb[3];
        *reinterpret_cast<float4*>(
            &C[row * N + bn + q * 64 + (tx << 2)]) = o;
      }
    }
}

// ---------------------------------------------------------------------------
// QK^T scores (scaled), lower-triangular 128x128 tiles only.
// Per (b,h): scores[q][k] = (1/8) * sum_d Q[q][d]*K[k][d]. Full hd=64 in LDS.
// Upper-tri tiles skipped (softmax writes the zeros). Diagonal tiles computed
// unmasked; softmax ignores cols > q and overwrites them with 0.
// ---------------------------------------------------------------------------
__global__ __launch_bounds__(256) void scores_kernel(
    const float* __restrict__ Q, const float* __restrict__ Kp,
    float* __restrict__ attn) {
  const int bh = blockIdx.y;
  const int b = bh >> 4;
  const int h = bh & 15;
  const int t = blockIdx.x;
  int qt = (int)((sqrtf(8.f * (float)t + 1.f) - 1.f) * 0.5f);
  while ((qt * (qt + 1)) / 2 > t) --qt;
  while (((qt + 1) * (qt + 2)) / 2 <= t) ++qt;
  const int kt = t - (qt * (qt + 1)) / 2;

  __shared__ float Qs[64][132];  // [d][q]
  __shared__ float Ks[64][132];  // [d][k]
  const int tid = threadIdx.x;
  const int tx = tid & 15;  // k dir
  const int ty = tid >> 4;  // q dir

  // Load 128 seq-rows x 64 d per operand, transposed into LDS.
  const int r = tid >> 1;             // seq row 0..127
  const int cbase = (tid & 1) << 5;   // 0 or 32
  const float* qg = Q + ((size_t)(b * SEQ + qt * 128 + r)) * D_MODEL + h * 64;
  const float* kg = Kp + ((size_t)(b * SEQ + kt * 128 + r)) * D_MODEL + h * 64;
#pragma unroll
  for (int u = 0; u < 8; ++u) {
    const int c = cbase + (u << 2);
    float4 q4 = *reinterpret_cast<const float4*>(qg + c);
    Qs[c + 0][r] = q4.x; Qs[c + 1][r] = q4.y;
    Qs[c + 2][r] = q4.z; Qs[c + 3][r] = q4.w;
    float4 k4 = *reinterpret_cast<const float4*>(kg + c);
    Ks[c + 0][r] = k4.x; Ks[c + 1][r] = k4.y;
    Ks[c + 2][r] = k4.z; Ks[c + 3][r] = k4.w;
  }
  __syncthreads();

  float acc[2][2][4][4] = {};
#pragma unroll 8
  for (int d = 0; d < 64; ++d) {
    float4 q0 = *reinterpret_cast<const float4*>(&Qs[d][ty << 2]);
    float4 q1 = *reinterpret_cast<const float4*>(&Qs[d][64 + (ty << 2)]);
    float4 k0 = *reinterpret_cast<const float4*>(&Ks[d][tx << 2]);
    float4 k1 = *reinterpret_cast<const float4*>(&Ks[d][64 + (tx << 2)]);
    const float qm[2][4] = {{q0.x, q0.y, q0.z, q0.w},
                            {q1.x, q1.y, q1.z, q1.w}};
    const float kn[2][4] = {{k0.x, k0.y, k0.z, k0.w},
                            {k1.x, k1.y, k1.z, k1.w}};
#pragma unroll
    for (int p = 0; p < 2; ++p)
#pragma unroll
      for (int q = 0; q < 2; ++q)
#pragma unroll
        for (int i = 0; i < 4; ++i)
#pragma unroll
          for (int j = 0; j < 4; ++j)
            acc[p][q][i][j] += qm[p][i] * kn[q][j];
  }

#pragma unroll
  for (int p = 0; p < 2; ++p)
#pragma unroll
    for (int i = 0; i < 4; ++i) {
      const size_t row =
          (size_t)bh * SEQ + qt * 128 + p * 64 + (ty << 2) + i;
#pragma unroll
      for (int q = 0; q < 2; ++q) {
        float4 o;
        o.x = acc[p][q][i][0] * 0.125f;
        o.y = acc[p][q][i][1] * 0.125f;
        o.z = acc[p][q][i][2] * 0.125f;
        o.w = acc[p][q][i][3] * 0.125f;
        *reinterpret_cast<float4*>(
            &attn[row * SEQ + kt * 128 + q * 64 + (tx << 2)]) = o;
      }
    }
}

// ---------------------------------------------------------------------------
// Row softmax over attn, causal. One block (256 thr) per row; 2048 = 8*256.
// Cols > q written as 0 (exp(-inf) = 0), matching reference semantics.
// ---------------------------------------------------------------------------
__global__ __launch_bounds__(256) void softmax_kernel(float* __restrict__ attn) {
  const size_t row = blockIdx.x;
  const int q = (int)(row & (SEQ - 1));
  const int n = q + 1;
  float* p = attn + row * (size_t)SEQ;
  const int tid = threadIdx.x;

  float v[8];
#pragma unroll
  for (int u = 0; u < 8; ++u) {
    const int i = tid + (u << 8);
    v[u] = (i < n) ? p[i] : -INFINITY;
  }
  float m = v[0];
#pragma unroll
  for (int u = 1; u < 8; ++u) m = fmaxf(m, v[u]);
#pragma unroll
  for (int off = 1; off < 64; off <<= 1) m = fmaxf(m, __shfl_xor(m, off, 64));
  __shared__ float redm[4];
  if ((tid & 63) == 0) redm[tid >> 6] = m;
  __syncthreads();
  m = fmaxf(fmaxf(redm[0], redm[1]), fmaxf(redm[2], redm[3]));

  float s = 0.f;
#pragma unroll
  for (int u = 0; u < 8; ++u) {
    const float e = expf(v[u] - m);
    v[u] = e;
    s += e;
  }
#pragma unroll
  for (int off = 1; off < 64; off <<= 1) s += __shfl_xor(s, off, 64);
  __shared__ float reds[4];
  if ((tid & 63) == 0) reds[tid >> 6] = s;
  __syncthreads();
  s = reds[0] + reds[1] + reds[2] + reds[3];

  const float inv = 1.f / s;
#pragma unroll
  for (int u = 0; u < 8; ++u) p[tid + (u << 8)] = v[u] * inv;
}

// ---------------------------------------------------------------------------
// ctx = attn @ V per (b,h). Output tile 128(q) x 64(hd); k-loop clipped at
// (qt+1)*128 (attn is exactly 0 beyond the causal boundary).
// ctx written merged-head (B*S, D) so the output GEMM is plain.
// ---------------------------------------------------------------------------
__global__ __launch_bounds__(256) void pv_kernel(
    const float* __restrict__ attn, const float* __restrict__ V,
    float* __restrict__ ctx) {
  const int qt = blockIdx.x;  // 0..15
  const int bh = blockIdx.y;
  const int b = bh >> 4;
  const int h = bh & 15;
  __shared__ float Ps[16][132];  // [k][q], transposed attn tile
  __shared__ float Vs[16][68];   // [k][d]
  const int tid = threadIdx.x;
  const int tx = tid & 15;  // d dir (covers 64)
  const int ty = tid >> 4;  // q dir
  float acc[2][4][4] = {};

  const int kmax = (qt + 1) * 128;
  const float* arow = attn + ((size_t)bh * SEQ + qt * 128) * SEQ;
  const int pr = tid >> 2, pc = (tid & 3) << 2;   // attn-tile load coords
  const int vr = tid >> 4, vc = (tid & 15) << 2;  // V-tile load coords

  for (int k0 = 0; k0 < kmax; k0 += 16) {
#pragma unroll
    for (int hh = 0; hh < 2; ++hh) {
      const int r = pr + hh * 64;
      float4 p4 =
          *reinterpret_cast<const float4*>(&arow[(size_t)r * SEQ + k0 + pc]);
      Ps[pc + 0][r] = p4.x; Ps[pc + 1][r] = p4.y;
      Ps[pc + 2][r] = p4.z; Ps[pc + 3][r] = p4.w;
    }
    float4 v4 = *reinterpret_cast<const float4*>(
        &V[(size_t)(b * SEQ + k0 + vr) * D_MODEL + h * 64 + vc]);
    *reinterpret_cast<float4*>(&Vs[vr][vc]) = v4;
    __syncthreads();
#pragma unroll
    for (int kk = 0; kk < 16; ++kk) {
      float4 a0 = *reinterpret_cast<const float4*>(&Ps[kk][ty << 2]);
      float4 a1 = *reinterpret_cast<const float4*>(&Ps[kk][64 + (ty << 2)]);
      float4 vv = *reinterpret_cast<const float4*>(&Vs[kk][tx << 2]);
      const float am[2][4] = {{a0.x, a0.y, a0.z, a0.w},
                              {a1.x, a1.y, a1.z, a1.w}};
      const float vn[4] = {vv.x, vv.y, vv.z, vv.w};
#pragma unroll
      for (int p = 0; p < 2; ++p)
#pragma unroll
        for (int i = 0; i < 4; ++i)
#pragma unroll
          for (int j = 0; j < 4; ++j)
            acc[p][i][j] += am[p][i] * vn[j];
    }
    __syncthreads();
  }

#pragma unroll
  for (int p = 0; p < 2; ++p)
#pragma unroll
    for (int i = 0; i < 4; ++i) {
      float4 o = {acc[p][i][0], acc[p][i][1], acc[p][i][2], acc[p][i][3]};
      *reinterpret_cast<float4*>(
          &ctx[(size_t)(b * SEQ + qt * 128 + p * 64 + (ty << 2) + i) *
                   D_MODEL +
               h * 64 + (tx << 2)]) = o;
    }
}

// ---------------------------------------------------------------------------
extern "C" void kernel_launch(void* const* d_in, const int* in_sizes, int n_in,
                              void* d_out, int out_size, void* d_ws,
                              size_t ws_size, hipStream_t stream) {
  const float* queries = (const float*)d_in[0];
  const float* keys = (const float*)d_in[1];
  const float* values = (const float*)d_in[2];
  const float* W_Q = (const float*)d_in[3];
  const float* b_Q = (const float*)d_in[4];
  const float* W_K = (const float*)d_in[5];
  const float* b_K = (const float*)d_in[6];
  const float* W_V = (const float*)d_in[7];
  const float* b_V = (const float*)d_in[8];
  const float* W_O = (const float*)d_in[9];
  const float* b_O = (const float*)d_in[10];

  float* out = (float*)d_out;                         // (B,S,D)
  float* attn = out + (size_t)BATCH * SEQ * D_MODEL;  // (B,H,S,S)

  const size_t proj_elems = (size_t)M_PROJ * D_MODEL;
  float* Q = (float*)d_ws;
  float* K = Q + proj_elems;
  float* V = K + proj_elems;
  float* ctx = V + proj_elems;

  const dim3 blk(256);
  const dim3 gproj(D_MODEL / 128, M_PROJ / 128);  // (8,64)

  gemm_bias_kernel<<<gproj, blk, 0, stream>>>(queries, W_Q, b_Q, Q, M_PROJ,
                                              D_MODEL, D_MODEL);
  gemm_bias_kernel<<<gproj, blk, 0, stream>>>(keys, W_K, b_K, K, M_PROJ,
                                              D_MODEL, D_MODEL);
  gemm_bias_kernel<<<gproj, blk, 0, stream>>>(values, W_V, b_V, V, M_PROJ,
                                              D_MODEL, D_MODEL);

  const int ntri = (SEQ / 128) * (SEQ / 128 + 1) / 2;  // 136
  scores_kernel<<<dim3(ntri, BATCH * NUM_HEADS), blk, 0, stream>>>(Q, K, attn);

  softmax_kernel<<<dim3(BATCH * NUM_HEADS * SEQ), blk, 0, stream>>>(attn);

  pv_kernel<<<dim3(SEQ / 128, BATCH * NUM_HEADS), blk, 0, stream>>>(attn, V,
                                                                    ctx);

  gemm_bias_kernel<<<gproj, blk, 0, stream>>>(ctx, W_O, b_O, out, M_PROJ,
                                              D_MODEL, D_MODEL);
}

// Round 5
// 2282.205 us; speedup vs baseline: 1.1772x; 1.1772x over previous
//
#include <hip/hip_runtime.h>
#include <hip/hip_bf16.h>
#include <math.h>

#define D_MODEL 1024
#define NUM_HEADS 16
#define HEAD_SIZE 64
#define SEQ 2048
#define BATCH 4
#define M_PROJ (BATCH * SEQ)  // 8192

typedef __attribute__((ext_vector_type(8))) short bf16x8;
typedef __attribute__((ext_vector_type(4))) float f32x4;

// ---------------------------------------------------------------------------
// bf16 helpers (RNE)
// ---------------------------------------------------------------------------
__device__ inline float bf2f(ushort u) {
  return __uint_as_float(((unsigned int)u) << 16);
}
__device__ inline ushort f2bf(float x) {
  unsigned int b = __float_as_uint(x);
  b += 0x7fffu + ((b >> 16) & 1u);
  return (ushort)(b >> 16);
}

__device__ inline void gload_lds16(const void* g, void* l) {
  __builtin_amdgcn_global_load_lds(
      (const __attribute__((address_space(1))) void*)g,
      (__attribute__((address_space(3))) void*)l, 16, 0, 0);
}

// ---------------------------------------------------------------------------
// Split fp32 -> bf16 hi/lo (elementwise, float4-vectorized, grid-stride)
// ---------------------------------------------------------------------------
__global__ __launch_bounds__(256) void split_kernel(
    const float* __restrict__ in, ushort* __restrict__ hi,
    ushort* __restrict__ lo, int n4) {
  for (int i = blockIdx.x * 256 + threadIdx.x; i < n4; i += gridDim.x * 256) {
    float4 v = reinterpret_cast<const float4*>(in)[i];
    const float xs[4] = {v.x, v.y, v.z, v.w};
    ushort hh[4], ll[4];
#pragma unroll
    for (int j = 0; j < 4; ++j) {
      hh[j] = f2bf(xs[j]);
      ll[j] = f2bf(xs[j] - bf2f(hh[j]));
    }
    ushort4 h4, l4;
    h4.x = hh[0]; h4.y = hh[1]; h4.z = hh[2]; h4.w = hh[3];
    l4.x = ll[0]; l4.y = ll[1]; l4.z = ll[2]; l4.w = ll[3];
    reinterpret_cast<ushort4*>(hi)[i] = h4;
    reinterpret_cast<ushort4*>(lo)[i] = l4;
  }
}

// ---------------------------------------------------------------------------
// W [K=1024, N=1024] fp32 -> Wt hi/lo [N,K] bf16 (transpose + split)
// ---------------------------------------------------------------------------
__global__ __launch_bounds__(256) void transpose_split_kernel(
    const float* __restrict__ W, ushort* __restrict__ tHi,
    ushort* __restrict__ tLo) {
  __shared__ float tile[64][65];
  const int kt = blockIdx.y << 6, nt = blockIdx.x << 6;
  const int tx = threadIdx.x & 15, ty = threadIdx.x >> 4;
#pragma unroll
  for (int u = 0; u < 4; ++u) {
    const int r = ty + (u << 4);
    float4 v = *reinterpret_cast<const float4*>(
        &W[(size_t)(kt + r) * D_MODEL + nt + (tx << 2)]);
    tile[r][(tx << 2) + 0] = v.x;
    tile[r][(tx << 2) + 1] = v.y;
    tile[r][(tx << 2) + 2] = v.z;
    tile[r][(tx << 2) + 3] = v.w;
  }
  __syncthreads();
#pragma unroll
  for (int u = 0; u < 4; ++u) {
    const int n = ty + (u << 4);
    ushort h[4], l[4];
#pragma unroll
    for (int i = 0; i < 4; ++i) {
      const float x = tile[(tx << 2) + i][n];  // = W[kt+tx*4+i][nt+n]
      h[i] = f2bf(x);
      l[i] = f2bf(x - bf2f(h[i]));
    }
    ushort4 h4, l4;
    h4.x = h[0]; h4.y = h[1]; h4.z = h[2]; h4.w = h[3];
    l4.x = l[0]; l4.y = l[1]; l4.z = l[2]; l4.w = l[3];
    *reinterpret_cast<ushort4*>(
        &tHi[(size_t)(nt + n) * D_MODEL + kt + (tx << 2)]) = h4;
    *reinterpret_cast<ushort4*>(
        &tLo[(size_t)(nt + n) * D_MODEL + kt + (tx << 2)]) = l4;
  }
}

// ---------------------------------------------------------------------------
// Split-bf16 MFMA GEMM: C[M,N] = (Ahi+Alo)[M,K] @ (Bhi+Blo)[N,K]^T + bias
// (3-term: hh + hl + lh). 128x128 tile, BK=32, 4 waves, 16x16x32 MFMA.
// LDS is fragment-major: part p, frag-block f (16 rows), lane slot l holds
// row f*16+(l&15), k = (l>>4)*8 .. +8. global_load_lds dest is linear;
// the *global source* is pre-permuted to this order (HK pattern).
// ---------------------------------------------------------------------------
__global__ __launch_bounds__(256) void mfma_gemm_kernel(
    const ushort* __restrict__ Ahi, const ushort* __restrict__ Alo,
    const ushort* __restrict__ Bhi, const ushort* __restrict__ Blo,
    const float* __restrict__ bias, float* __restrict__ C,
    int M, int N, int K) {
  __shared__ short lds[16384];  // 32 KB: 4 parts x 8 frag-blocks x 512 shorts
  const int tid = threadIdx.x;
  const int wid = tid >> 6, lane = tid & 63;

  // bijective XCD swizzle (gridDim.x % 8 == 0 here)
  const int nbn = N >> 7;
  const int cpx = gridDim.x >> 3;
  const int swz = (blockIdx.x & 7) * cpx + (blockIdx.x >> 3);
  const int bm = (swz / nbn) << 7;
  const int bn = (swz % nbn) << 7;

  const int rowoff = lane & 15;
  const int koff = (lane >> 4) << 3;
  const int wr = wid >> 1, wc = wid & 1;

  f32x4 acc[4][4] = {};

  for (int k0 = 0; k0 < K; k0 += 32) {
#pragma unroll
    for (int iss = 0; iss < 2; ++iss) {
      const int f = (iss << 2) + wid;  // frag block 0..7 (wave-uniform)
      const size_t arow = (size_t)(bm + f * 16 + rowoff) * K + k0 + koff;
      const size_t brow = (size_t)(bn + f * 16 + rowoff) * K + k0 + koff;
      gload_lds16(Ahi + arow, &lds[0 * 4096 + f * 512]);
      gload_lds16(Alo + arow, &lds[1 * 4096 + f * 512]);
      gload_lds16(Bhi + brow, &lds[2 * 4096 + f * 512]);
      gload_lds16(Blo + brow, &lds[3 * 4096 + f * 512]);
    }
    __syncthreads();  // drains vmcnt before barrier

    bf16x8 ah[4], al[4], bh[4], bl[4];
#pragma unroll
    for (int i = 0; i < 4; ++i) {
      const int fa = wr * 4 + i;
      const int fb = wc * 4 + i;
      ah[i] = *reinterpret_cast<const bf16x8*>(&lds[0 * 4096 + fa * 512 + lane * 8]);
      al[i] = *reinterpret_cast<const bf16x8*>(&lds[1 * 4096 + fa * 512 + lane * 8]);
      bh[i] = *reinterpret_cast<const bf16x8*>(&lds[2 * 4096 + fb * 512 + lane * 8]);
      bl[i] = *reinterpret_cast<const bf16x8*>(&lds[3 * 4096 + fb * 512 + lane * 8]);
    }
#pragma unroll
    for (int mi = 0; mi < 4; ++mi)
#pragma unroll
      for (int ni = 0; ni < 4; ++ni) {
        acc[mi][ni] = __builtin_amdgcn_mfma_f32_16x16x32_bf16(
            ah[mi], bh[ni], acc[mi][ni], 0, 0, 0);
        acc[mi][ni] = __builtin_amdgcn_mfma_f32_16x16x32_bf16(
            ah[mi], bl[ni], acc[mi][ni], 0, 0, 0);
        acc[mi][ni] = __builtin_amdgcn_mfma_f32_16x16x32_bf16(
            al[mi], bh[ni], acc[mi][ni], 0, 0, 0);
      }
    __syncthreads();
  }

  // Epilogue: C/D layout col=lane&15, row=(lane>>4)*4+j (m89-verified)
  const int crowbase = bm + wr * 64 + ((lane >> 4) << 2);
  const int ccolbase = bn + wc * 64 + (lane & 15);
#pragma unroll
  for (int ni = 0; ni < 4; ++ni) {
    const int col = ccolbase + ni * 16;
    const float bv = bias[col];
#pragma unroll
    for (int mi = 0; mi < 4; ++mi) {
      const int row = crowbase + mi * 16;
#pragma unroll
      for (int j = 0; j < 4; ++j)
        C[(size_t)(row + j) * N + col] = acc[mi][ni][j] + bv;
    }
  }
}

// ---------------------------------------------------------------------------
// MFMA QK^T scores: same recipe as mfma_gemm (A=Q rows, B=K rows, k=hd=64,
// two 32-k steps). Lower-triangular 128x128 tiles only; x0.125 scale in
// epilogue; no masking (softmax ignores cols > q). LDS 64 KB:
// part(4) x fblock(8) x kstep(2) x 512 shorts, fragment-major.
// ---------------------------------------------------------------------------
__global__ __launch_bounds__(256) void scores_mfma_kernel(
    const ushort* __restrict__ Qhi, const ushort* __restrict__ Qlo,
    const ushort* __restrict__ Khi, const ushort* __restrict__ Klo,
    float* __restrict__ attn) {
  __shared__ short lds[32768];  // 64 KB
  const int tid = threadIdx.x;
  const int wid = tid >> 6, lane = tid & 63;
  const int bh = blockIdx.y;
  const int b = bh >> 4;
  const int h = bh & 15;
  const int t = blockIdx.x;
  int qt = (int)((sqrtf(8.f * (float)t + 1.f) - 1.f) * 0.5f);
  while ((qt * (qt + 1)) / 2 > t) --qt;
  while (((qt + 1) * (qt + 2)) / 2 <= t) ++qt;
  const int kt = t - (qt * (qt + 1)) / 2;

  const int rowoff = lane & 15;
  const int koff = (lane >> 4) << 3;
  const int wr = wid >> 1, wc = wid & 1;

  const size_t qbase = (size_t)(b * SEQ + qt * 128) * D_MODEL + h * 64;
  const size_t kbase = (size_t)(b * SEQ + kt * 128) * D_MODEL + h * 64;
#pragma unroll
  for (int iss = 0; iss < 2; ++iss) {
    const int f = (iss << 2) + wid;  // wave-uniform fblock
#pragma unroll
    for (int s = 0; s < 2; ++s) {
      const size_t qa = qbase + (size_t)(f * 16 + rowoff) * D_MODEL + s * 32 + koff;
      const size_t ka = kbase + (size_t)(f * 16 + rowoff) * D_MODEL + s * 32 + koff;
      const int lo_ = (f * 2 + s) * 512;  // wave-uniform LDS offset
      gload_lds16(Qhi + qa, &lds[0 * 8192 + lo_]);
      gload_lds16(Qlo + qa, &lds[1 * 8192 + lo_]);
      gload_lds16(Khi + ka, &lds[2 * 8192 + lo_]);
      gload_lds16(Klo + ka, &lds[3 * 8192 + lo_]);
    }
  }
  __syncthreads();

  f32x4 acc[4][4] = {};
#pragma unroll
  for (int s = 0; s < 2; ++s) {
    bf16x8 ah[4], al[4], kh[4], kl[4];
#pragma unroll
    for (int i = 0; i < 4; ++i) {
      const int fa = ((wr * 4 + i) * 2 + s) * 512 + lane * 8;
      const int fb = ((wc * 4 + i) * 2 + s) * 512 + lane * 8;
      ah[i] = *reinterpret_cast<const bf16x8*>(&lds[0 * 8192 + fa]);
      al[i] = *reinterpret_cast<const bf16x8*>(&lds[1 * 8192 + fa]);
      kh[i] = *reinterpret_cast<const bf16x8*>(&lds[2 * 8192 + fb]);
      kl[i] = *reinterpret_cast<const bf16x8*>(&lds[3 * 8192 + fb]);
    }
#pragma unroll
    for (int mi = 0; mi < 4; ++mi)
#pragma unroll
      for (int ni = 0; ni < 4; ++ni) {
        acc[mi][ni] = __builtin_amdgcn_mfma_f32_16x16x32_bf16(
            ah[mi], kh[ni], acc[mi][ni], 0, 0, 0);
        acc[mi][ni] = __builtin_amdgcn_mfma_f32_16x16x32_bf16(
            ah[mi], kl[ni], acc[mi][ni], 0, 0, 0);
        acc[mi][ni] = __builtin_amdgcn_mfma_f32_16x16x32_bf16(
            al[mi], kh[ni], acc[mi][ni], 0, 0, 0);
      }
  }

  const int crowbase = qt * 128 + wr * 64 + ((lane >> 4) << 2);
  const int ccolbase = kt * 128 + wc * 64 + (lane & 15);
#pragma unroll
  for (int ni = 0; ni < 4; ++ni) {
    const int col = ccolbase + ni * 16;
#pragma unroll
    for (int mi = 0; mi < 4; ++mi) {
      const int row = crowbase + mi * 16;
#pragma unroll
      for (int j = 0; j < 4; ++j)
        attn[((size_t)bh * SEQ + row + j) * SEQ + col] = acc[mi][ni][j] * 0.125f;
    }
  }
}

// ---------------------------------------------------------------------------
// Row softmax, causal (unchanged). Reads only cols <= q (written tiles),
// writes the full row including the causal zeros.
// ---------------------------------------------------------------------------
__global__ __launch_bounds__(256) void softmax_kernel(float* __restrict__ attn) {
  const size_t row = blockIdx.x;
  const int q = (int)(row & (SEQ - 1));
  const int n = q + 1;
  float* p = attn + row * (size_t)SEQ;
  const int tid = threadIdx.x;

  float v[8];
#pragma unroll
  for (int u = 0; u < 8; ++u) {
    const int i = tid + (u << 8);
    v[u] = (i < n) ? p[i] : -INFINITY;
  }
  float m = v[0];
#pragma unroll
  for (int u = 1; u < 8; ++u) m = fmaxf(m, v[u]);
#pragma unroll
  for (int off = 1; off < 64; off <<= 1) m = fmaxf(m, __shfl_xor(m, off, 64));
  __shared__ float redm[4];
  if ((tid & 63) == 0) redm[tid >> 6] = m;
  __syncthreads();
  m = fmaxf(fmaxf(redm[0], redm[1]), fmaxf(redm[2], redm[3]));

  float s = 0.f;
#pragma unroll
  for (int u = 0; u < 8; ++u) {
    const float e = expf(v[u] - m);
    v[u] = e;
    s += e;
  }
#pragma unroll
  for (int off = 1; off < 64; off <<= 1) s += __shfl_xor(s, off, 64);
  __shared__ float reds[4];
  if ((tid & 63) == 0) reds[tid >> 6] = s;
  __syncthreads();
  s = reds[0] + reds[1] + reds[2] + reds[3];

  const float inv = 1.f / s;
#pragma unroll
  for (int u = 0; u < 8; ++u) p[tid + (u << 8)] = v[u] * inv;
}

// ---------------------------------------------------------------------------
// ctx = attn @ V per (b,h), causal-clipped k-loop (unchanged fp32).
// ---------------------------------------------------------------------------
__global__ __launch_bounds__(256) void pv_kernel(
    const float* __restrict__ attn, const float* __restrict__ V,
    float* __restrict__ ctx) {
  const int qt = blockIdx.x;
  const int bh = blockIdx.y;
  const int b = bh >> 4;
  const int h = bh & 15;
  __shared__ float Ps[16][132];
  __shared__ float Vs[16][68];
  const int tid = threadIdx.x;
  const int tx = tid & 15;
  const int ty = tid >> 4;
  float acc[2][4][4] = {};

  const int kmax = (qt + 1) * 128;
  const float* arow = attn + ((size_t)bh * SEQ + qt * 128) * SEQ;
  const int pr = tid >> 2, pc = (tid & 3) << 2;
  const int vr = tid >> 4, vc = (tid & 15) << 2;

  for (int k0 = 0; k0 < kmax; k0 += 16) {
#pragma unroll
    for (int hh = 0; hh < 2; ++hh) {
      const int r = pr + hh * 64;
      float4 p4 =
          *reinterpret_cast<const float4*>(&arow[(size_t)r * SEQ + k0 + pc]);
      Ps[pc + 0][r] = p4.x; Ps[pc + 1][r] = p4.y;
      Ps[pc + 2][r] = p4.z; Ps[pc + 3][r] = p4.w;
    }
    float4 v4 = *reinterpret_cast<const float4*>(
        &V[(size_t)(b * SEQ + k0 + vr) * D_MODEL + h * 64 + vc]);
    *reinterpret_cast<float4*>(&Vs[vr][vc]) = v4;
    __syncthreads();
#pragma unroll
    for (int kk = 0; kk < 16; ++kk) {
      float4 a0 = *reinterpret_cast<const float4*>(&Ps[kk][ty << 2]);
      float4 a1 = *reinterpret_cast<const float4*>(&Ps[kk][64 + (ty << 2)]);
      float4 vv = *reinterpret_cast<const float4*>(&Vs[kk][tx << 2]);
      const float am[2][4] = {{a0.x, a0.y, a0.z, a0.w},
                              {a1.x, a1.y, a1.z, a1.w}};
      const float vn[4] = {vv.x, vv.y, vv.z, vv.w};
#pragma unroll
      for (int p = 0; p < 2; ++p)
#pragma unroll
        for (int i = 0; i < 4; ++i)
#pragma unroll
          for (int j = 0; j < 4; ++j)
            acc[p][i][j] += am[p][i] * vn[j];
    }
    __syncthreads();
  }

#pragma unroll
  for (int p = 0; p < 2; ++p)
#pragma unroll
    for (int i = 0; i < 4; ++i) {
      float4 o = {acc[p][i][0], acc[p][i][1], acc[p][i][2], acc[p][i][3]};
      *reinterpret_cast<float4*>(
          &ctx[(size_t)(b * SEQ + qt * 128 + p * 64 + (ty << 2) + i) *
                   D_MODEL + h * 64 + (tx << 2)]) = o;
    }
}

// ---------------------------------------------------------------------------
extern "C" void kernel_launch(void* const* d_in, const int* in_sizes, int n_in,
                              void* d_out, int out_size, void* d_ws,
                              size_t ws_size, hipStream_t stream) {
  const float* queries = (const float*)d_in[0];
  const float* keys = (const float*)d_in[1];
  const float* values = (const float*)d_in[2];
  const float* W_Q = (const float*)d_in[3];
  const float* b_Q = (const float*)d_in[4];
  const float* W_K = (const float*)d_in[5];
  const float* b_K = (const float*)d_in[6];
  const float* W_V = (const float*)d_in[7];
  const float* b_V = (const float*)d_in[8];
  const float* W_O = (const float*)d_in[9];
  const float* b_O = (const float*)d_in[10];

  float* out = (float*)d_out;                         // (B,S,D)
  float* attn = out + (size_t)BATCH * SEQ * D_MODEL;  // (B,H,S,S)

  const size_t PE = (size_t)M_PROJ * D_MODEL;  // 8388608
  float* Q = (float*)d_ws;
  float* K = Q + PE;
  float* V = K + PE;
  float* ctx = V + PE;
  ushort* Xhi = (ushort*)(ctx + PE);
  ushort* Xlo = Xhi + PE;
  ushort* Wthi = Xlo + PE;
  ushort* Wtlo = Wthi + (size_t)D_MODEL * D_MODEL;
  ushort* Qhi = Wtlo + (size_t)D_MODEL * D_MODEL;
  ushort* Qlo = Qhi + PE;
  ushort* Khi = Qlo + PE;
  ushort* Klo = Khi + PE;
  // total ws use ~= 239 MB (ws is multi-GB per the fill-buffer sizes)

  const dim3 blk(256);
  const int n4 = (int)(PE / 4);

  auto do_gemm = [&](const float* X, const float* W, const float* b,
                     float* Cout) {
    split_kernel<<<2048, blk, 0, stream>>>(X, Xhi, Xlo, n4);
    transpose_split_kernel<<<dim3(16, 16), blk, 0, stream>>>(W, Wthi, Wtlo);
    mfma_gemm_kernel<<<dim3(512), blk, 0, stream>>>(
        Xhi, Xlo, Wthi, Wtlo, b, Cout, M_PROJ, D_MODEL, D_MODEL);
  };

  do_gemm(queries, W_Q, b_Q, Q);
  do_gemm(keys, W_K, b_K, K);
  do_gemm(values, W_V, b_V, V);

  split_kernel<<<2048, blk, 0, stream>>>(Q, Qhi, Qlo, n4);
  split_kernel<<<2048, blk, 0, stream>>>(K, Khi, Klo, n4);

  const int ntri = (SEQ / 128) * (SEQ / 128 + 1) / 2;  // 136
  scores_mfma_kernel<<<dim3(ntri, BATCH * NUM_HEADS), blk, 0, stream>>>(
      Qhi, Qlo, Khi, Klo, attn);

  softmax_kernel<<<dim3(BATCH * NUM_HEADS * SEQ), blk, 0, stream>>>(attn);

  pv_kernel<<<dim3(SEQ / 128, BATCH * NUM_HEADS), blk, 0, stream>>>(attn, V,
                                                                    ctx);

  do_gemm(ctx, W_O, b_O, out);
}

// Round 6
// 2180.573 us; speedup vs baseline: 1.2321x; 1.0466x over previous
//
#include <hip/hip_runtime.h>
#include <hip/hip_bf16.h>
#include <math.h>

#define D_MODEL 1024
#define NUM_HEADS 16
#define HEAD_SIZE 64
#define SEQ 2048
#define BATCH 4
#define M_PROJ (BATCH * SEQ)  // 8192

typedef __attribute__((ext_vector_type(8))) short bf16x8;
typedef __attribute__((ext_vector_type(4))) float f32x4;

// ---------------------------------------------------------------------------
// bf16 helpers (RNE)
// ---------------------------------------------------------------------------
__device__ inline float bf2f(ushort u) {
  return __uint_as_float(((unsigned int)u) << 16);
}
__device__ inline ushort f2bf(float x) {
  unsigned int b = __float_as_uint(x);
  b += 0x7fffu + ((b >> 16) & 1u);
  return (ushort)(b >> 16);
}

__device__ inline void gload_lds16(const void* g, void* l) {
  __builtin_amdgcn_global_load_lds(
      (const __attribute__((address_space(1))) void*)g,
      (__attribute__((address_space(3))) void*)l, 16, 0, 0);
}

// ---------------------------------------------------------------------------
// Split fp32 -> bf16 hi/lo (inputs only now)
// ---------------------------------------------------------------------------
__global__ __launch_bounds__(256) void split_kernel(
    const float* __restrict__ in, ushort* __restrict__ hi,
    ushort* __restrict__ lo, int n4) {
  for (int i = blockIdx.x * 256 + threadIdx.x; i < n4; i += gridDim.x * 256) {
    float4 v = reinterpret_cast<const float4*>(in)[i];
    const float xs[4] = {v.x, v.y, v.z, v.w};
    ushort hh[4], ll[4];
#pragma unroll
    for (int j = 0; j < 4; ++j) {
      hh[j] = f2bf(xs[j]);
      ll[j] = f2bf(xs[j] - bf2f(hh[j]));
    }
    ushort4 h4, l4;
    h4.x = hh[0]; h4.y = hh[1]; h4.z = hh[2]; h4.w = hh[3];
    l4.x = ll[0]; l4.y = ll[1]; l4.z = ll[2]; l4.w = ll[3];
    reinterpret_cast<ushort4*>(hi)[i] = h4;
    reinterpret_cast<ushort4*>(lo)[i] = l4;
  }
}

// ---------------------------------------------------------------------------
// W [K,N] fp32 -> Wt hi/lo [N,K] bf16 (transpose + split)
// ---------------------------------------------------------------------------
__global__ __launch_bounds__(256) void transpose_split_kernel(
    const float* __restrict__ W, ushort* __restrict__ tHi,
    ushort* __restrict__ tLo) {
  __shared__ float tile[64][65];
  const int kt = blockIdx.y << 6, nt = blockIdx.x << 6;
  const int tx = threadIdx.x & 15, ty = threadIdx.x >> 4;
#pragma unroll
  for (int u = 0; u < 4; ++u) {
    const int r = ty + (u << 4);
    float4 v = *reinterpret_cast<const float4*>(
        &W[(size_t)(kt + r) * D_MODEL + nt + (tx << 2)]);
    tile[r][(tx << 2) + 0] = v.x;
    tile[r][(tx << 2) + 1] = v.y;
    tile[r][(tx << 2) + 2] = v.z;
    tile[r][(tx << 2) + 3] = v.w;
  }
  __syncthreads();
#pragma unroll
  for (int u = 0; u < 4; ++u) {
    const int n = ty + (u << 4);
    ushort h[4], l[4];
#pragma unroll
    for (int i = 0; i < 4; ++i) {
      const float x = tile[(tx << 2) + i][n];
      h[i] = f2bf(x);
      l[i] = f2bf(x - bf2f(h[i]));
    }
    ushort4 h4, l4;
    h4.x = h[0]; h4.y = h[1]; h4.z = h[2]; h4.w = h[3];
    l4.x = l[0]; l4.y = l[1]; l4.z = l[2]; l4.w = l[3];
    *reinterpret_cast<ushort4*>(
        &tHi[(size_t)(nt + n) * D_MODEL + kt + (tx << 2)]) = h4;
    *reinterpret_cast<ushort4*>(
        &tLo[(size_t)(nt + n) * D_MODEL + kt + (tx << 2)]) = l4;
  }
}

// ---------------------------------------------------------------------------
// Split-bf16 MFMA GEMM (3-term), 128x128 tile, BK=32, 4 waves.
// MODE 0: write fp32 C. MODE 1: write bf16 hi/lo split of C ([M][N]).
// MODE 2: write bf16 hi/lo of C transposed per-head: Vt[(b*16+h)*64+d][s],
//         where (b = row>>11, s = row&2047, col = h*64+d) -> idx (b<<10|col).
// ---------------------------------------------------------------------------
template <int MODE>
__global__ __launch_bounds__(256) void mfma_gemm_kernel(
    const ushort* __restrict__ Ahi, const ushort* __restrict__ Alo,
    const ushort* __restrict__ Bhi, const ushort* __restrict__ Blo,
    const float* __restrict__ bias, float* __restrict__ Cf,
    ushort* __restrict__ Chi, ushort* __restrict__ Clo, int M, int N, int K) {
  __shared__ short lds[16384];  // 32 KB: 4 parts x 8 frag-blocks x 512 shorts
  const int tid = threadIdx.x;
  const int wid = tid >> 6, lane = tid & 63;

  const int nbn = N >> 7;
  const int cpx = gridDim.x >> 3;
  const int swz = (blockIdx.x & 7) * cpx + (blockIdx.x >> 3);
  const int bm = (swz / nbn) << 7;
  const int bn = (swz % nbn) << 7;

  const int rowoff = lane & 15;
  const int koff = (lane >> 4) << 3;
  const int wr = wid >> 1, wc = wid & 1;

  f32x4 acc[4][4] = {};

  for (int k0 = 0; k0 < K; k0 += 32) {
#pragma unroll
    for (int iss = 0; iss < 2; ++iss) {
      const int f = (iss << 2) + wid;  // wave-uniform fblock
      const size_t arow = (size_t)(bm + f * 16 + rowoff) * K + k0 + koff;
      const size_t brow = (size_t)(bn + f * 16 + rowoff) * K + k0 + koff;
      gload_lds16(Ahi + arow, &lds[0 * 4096 + f * 512]);
      gload_lds16(Alo + arow, &lds[1 * 4096 + f * 512]);
      gload_lds16(Bhi + brow, &lds[2 * 4096 + f * 512]);
      gload_lds16(Blo + brow, &lds[3 * 4096 + f * 512]);
    }
    __syncthreads();

    bf16x8 ah[4], al[4], bh[4], bl[4];
#pragma unroll
    for (int i = 0; i < 4; ++i) {
      const int fa = wr * 4 + i;
      const int fb = wc * 4 + i;
      ah[i] = *reinterpret_cast<const bf16x8*>(&lds[0 * 4096 + fa * 512 + lane * 8]);
      al[i] = *reinterpret_cast<const bf16x8*>(&lds[1 * 4096 + fa * 512 + lane * 8]);
      bh[i] = *reinterpret_cast<const bf16x8*>(&lds[2 * 4096 + fb * 512 + lane * 8]);
      bl[i] = *reinterpret_cast<const bf16x8*>(&lds[3 * 4096 + fb * 512 + lane * 8]);
    }
#pragma unroll
    for (int mi = 0; mi < 4; ++mi)
#pragma unroll
      for (int ni = 0; ni < 4; ++ni) {
        acc[mi][ni] = __builtin_amdgcn_mfma_f32_16x16x32_bf16(
            ah[mi], bh[ni], acc[mi][ni], 0, 0, 0);
        acc[mi][ni] = __builtin_amdgcn_mfma_f32_16x16x32_bf16(
            ah[mi], bl[ni], acc[mi][ni], 0, 0, 0);
        acc[mi][ni] = __builtin_amdgcn_mfma_f32_16x16x32_bf16(
            al[mi], bh[ni], acc[mi][ni], 0, 0, 0);
      }
    __syncthreads();
  }

  // C/D layout: col=lane&15, row=(lane>>4)*4+j (m89-verified)
  const int crowbase = bm + wr * 64 + ((lane >> 4) << 2);
  const int ccolbase = bn + wc * 64 + (lane & 15);
#pragma unroll
  for (int ni = 0; ni < 4; ++ni) {
    const int col = ccolbase + ni * 16;
    const float bv = bias[col];
#pragma unroll
    for (int mi = 0; mi < 4; ++mi) {
      const int row0 = crowbase + mi * 16;
      if constexpr (MODE == 0) {
#pragma unroll
        for (int j = 0; j < 4; ++j)
          Cf[(size_t)(row0 + j) * N + col] = acc[mi][ni][j] + bv;
      } else if constexpr (MODE == 1) {
#pragma unroll
        for (int j = 0; j < 4; ++j) {
          const float v = acc[mi][ni][j] + bv;
          const ushort h = f2bf(v);
          Chi[(size_t)(row0 + j) * N + col] = h;
          Clo[(size_t)(row0 + j) * N + col] = f2bf(v - bf2f(h));
        }
      } else {  // MODE 2: transposed per-head, ushort4 along s
        ushort4 h4, l4;
        ushort* hp = reinterpret_cast<ushort*>(&h4);
        ushort* lp = reinterpret_cast<ushort*>(&l4);
#pragma unroll
        for (int j = 0; j < 4; ++j) {
          const float v = acc[mi][ni][j] + bv;
          hp[j] = f2bf(v);
          lp[j] = f2bf(v - bf2f(hp[j]));
        }
        const size_t vt = ((size_t)((row0 >> 11) << 10) + col) * SEQ +
                          (row0 & (SEQ - 1));
        *reinterpret_cast<ushort4*>(&Chi[vt]) = h4;
        *reinterpret_cast<ushort4*>(&Clo[vt]) = l4;
      }
    }
  }
}

// ---------------------------------------------------------------------------
// MFMA QK^T scores (3-term), lower-triangular 128x128 tiles only.
// ---------------------------------------------------------------------------
__global__ __launch_bounds__(256) void scores_mfma_kernel(
    const ushort* __restrict__ Qhi, const ushort* __restrict__ Qlo,
    const ushort* __restrict__ Khi, const ushort* __restrict__ Klo,
    float* __restrict__ attn) {
  __shared__ short lds[32768];  // 64 KB
  const int tid = threadIdx.x;
  const int wid = tid >> 6, lane = tid & 63;
  const int bh = blockIdx.y;
  const int b = bh >> 4;
  const int h = bh & 15;
  const int t = blockIdx.x;
  int qt = (int)((sqrtf(8.f * (float)t + 1.f) - 1.f) * 0.5f);
  while ((qt * (qt + 1)) / 2 > t) --qt;
  while (((qt + 1) * (qt + 2)) / 2 <= t) ++qt;
  const int kt = t - (qt * (qt + 1)) / 2;

  const int rowoff = lane & 15;
  const int koff = (lane >> 4) << 3;
  const int wr = wid >> 1, wc = wid & 1;

  const size_t qbase = (size_t)(b * SEQ + qt * 128) * D_MODEL + h * 64;
  const size_t kbase = (size_t)(b * SEQ + kt * 128) * D_MODEL + h * 64;
#pragma unroll
  for (int iss = 0; iss < 2; ++iss) {
    const int f = (iss << 2) + wid;
#pragma unroll
    for (int s = 0; s < 2; ++s) {
      const size_t qa = qbase + (size_t)(f * 16 + rowoff) * D_MODEL + s * 32 + koff;
      const size_t ka = kbase + (size_t)(f * 16 + rowoff) * D_MODEL + s * 32 + koff;
      const int lo_ = (f * 2 + s) * 512;
      gload_lds16(Qhi + qa, &lds[0 * 8192 + lo_]);
      gload_lds16(Qlo + qa, &lds[1 * 8192 + lo_]);
      gload_lds16(Khi + ka, &lds[2 * 8192 + lo_]);
      gload_lds16(Klo + ka, &lds[3 * 8192 + lo_]);
    }
  }
  __syncthreads();

  f32x4 acc[4][4] = {};
#pragma unroll
  for (int s = 0; s < 2; ++s) {
    bf16x8 ah[4], al[4], kh[4], kl[4];
#pragma unroll
    for (int i = 0; i < 4; ++i) {
      const int fa = ((wr * 4 + i) * 2 + s) * 512 + lane * 8;
      const int fb = ((wc * 4 + i) * 2 + s) * 512 + lane * 8;
      ah[i] = *reinterpret_cast<const bf16x8*>(&lds[0 * 8192 + fa]);
      al[i] = *reinterpret_cast<const bf16x8*>(&lds[1 * 8192 + fa]);
      kh[i] = *reinterpret_cast<const bf16x8*>(&lds[2 * 8192 + fb]);
      kl[i] = *reinterpret_cast<const bf16x8*>(&lds[3 * 8192 + fb]);
    }
#pragma unroll
    for (int mi = 0; mi < 4; ++mi)
#pragma unroll
      for (int ni = 0; ni < 4; ++ni) {
        acc[mi][ni] = __builtin_amdgcn_mfma_f32_16x16x32_bf16(
            ah[mi], kh[ni], acc[mi][ni], 0, 0, 0);
        acc[mi][ni] = __builtin_amdgcn_mfma_f32_16x16x32_bf16(
            ah[mi], kl[ni], acc[mi][ni], 0, 0, 0);
        acc[mi][ni] = __builtin_amdgcn_mfma_f32_16x16x32_bf16(
            al[mi], kh[ni], acc[mi][ni], 0, 0, 0);
      }
  }

  const int crowbase = qt * 128 + wr * 64 + ((lane >> 4) << 2);
  const int ccolbase = kt * 128 + wc * 64 + (lane & 15);
#pragma unroll
  for (int ni = 0; ni < 4; ++ni) {
    const int col = ccolbase + ni * 16;
#pragma unroll
    for (int mi = 0; mi < 4; ++mi) {
      const int row = crowbase + mi * 16;
#pragma unroll
      for (int j = 0; j < 4; ++j)
        attn[((size_t)bh * SEQ + row + j) * SEQ + col] = acc[mi][ni][j] * 0.125f;
    }
  }
}

// ---------------------------------------------------------------------------
// Row softmax, causal; writes fp32 attn (output) AND bf16 P (for PV-MFMA).
// ---------------------------------------------------------------------------
__global__ __launch_bounds__(256) void softmax_kernel(
    float* __restrict__ attn, ushort* __restrict__ Pout) {
  const size_t row = blockIdx.x;
  const int q = (int)(row & (SEQ - 1));
  const int n = q + 1;
  float* p = attn + row * (size_t)SEQ;
  ushort* pb = Pout + row * (size_t)SEQ;
  const int tid = threadIdx.x;

  float v[8];
#pragma unroll
  for (int u = 0; u < 8; ++u) {
    const int i = tid + (u << 8);
    v[u] = (i < n) ? p[i] : -INFINITY;
  }
  float m = v[0];
#pragma unroll
  for (int u = 1; u < 8; ++u) m = fmaxf(m, v[u]);
#pragma unroll
  for (int off = 1; off < 64; off <<= 1) m = fmaxf(m, __shfl_xor(m, off, 64));
  __shared__ float redm[4];
  if ((tid & 63) == 0) redm[tid >> 6] = m;
  __syncthreads();
  m = fmaxf(fmaxf(redm[0], redm[1]), fmaxf(redm[2], redm[3]));

  float s = 0.f;
#pragma unroll
  for (int u = 0; u < 8; ++u) {
    const float e = expf(v[u] - m);
    v[u] = e;
    s += e;
  }
#pragma unroll
  for (int off = 1; off < 64; off <<= 1) s += __shfl_xor(s, off, 64);
  __shared__ float reds[4];
  if ((tid & 63) == 0) reds[tid >> 6] = s;
  __syncthreads();
  s = reds[0] + reds[1] + reds[2] + reds[3];

  const float inv = 1.f / s;
#pragma unroll
  for (int u = 0; u < 8; ++u) {
    const float pv = v[u] * inv;
    p[tid + (u << 8)] = pv;
    pb[tid + (u << 8)] = f2bf(pv);
  }
}

// ---------------------------------------------------------------------------
// PV MFMA: ctx[q][d] = sum_k P[q][k] * V[k][d], per (b,h), causal-clipped.
// P bf16 plain (A); Vt hi/lo bf16 (B, [bh*64+d][S] rows) -> 2-term.
// Block tile 128(q) x 64(d), 4 waves (2x2), BK=32.
// Epilogue writes ctx hi/lo bf16 (merged-head [M][1024]) for out-GEMM.
// ---------------------------------------------------------------------------
__global__ __launch_bounds__(256) void pv_mfma_kernel(
    const ushort* __restrict__ P, const ushort* __restrict__ Vthi,
    const ushort* __restrict__ Vtlo, ushort* __restrict__ ctxHi,
    ushort* __restrict__ ctxLo) {
  __shared__ short lds[8192];  // 16 KB: A 8x512 | Bhi 4x512 | Blo 4x512
  const int tid = threadIdx.x;
  const int wid = tid >> 6, lane = tid & 63;
  const int qt = blockIdx.x;
  const int bh = blockIdx.y;
  const int b = bh >> 4;
  const int h = bh & 15;

  const int rowoff = lane & 15;
  const int koff = (lane >> 4) << 3;
  const int wr = wid >> 1, wc = wid & 1;

  const size_t pbase = (size_t)bh * SEQ * SEQ + (size_t)(qt * 128) * SEQ;
  const size_t vbase = (size_t)bh * 64 * SEQ;

  f32x4 acc[4][2] = {};
  const int kmax = (qt + 1) * 128;

  for (int k0 = 0; k0 < kmax; k0 += 32) {
    // A: fblocks 2*wid, 2*wid+1 ; B: g = wid (hi and lo)
#pragma unroll
    for (int u = 0; u < 2; ++u) {
      const int f = 2 * wid + u;
      const size_t pa = pbase + (size_t)(f * 16 + rowoff) * SEQ + k0 + koff;
      gload_lds16(P + pa, &lds[f * 512]);
    }
    const size_t va = vbase + (size_t)(wid * 16 + rowoff) * SEQ + k0 + koff;
    gload_lds16(Vthi + va, &lds[4096 + wid * 512]);
    gload_lds16(Vtlo + va, &lds[6144 + wid * 512]);
    __syncthreads();

    bf16x8 a[4], bhf[2], blf[2];
#pragma unroll
    for (int i = 0; i < 4; ++i)
      a[i] = *reinterpret_cast<const bf16x8*>(&lds[(wr * 4 + i) * 512 + lane * 8]);
#pragma unroll
    for (int i = 0; i < 2; ++i) {
      bhf[i] = *reinterpret_cast<const bf16x8*>(
          &lds[4096 + (wc * 2 + i) * 512 + lane * 8]);
      blf[i] = *reinterpret_cast<const bf16x8*>(
          &lds[6144 + (wc * 2 + i) * 512 + lane * 8]);
    }
#pragma unroll
    for (int mi = 0; mi < 4; ++mi)
#pragma unroll
      for (int ni = 0; ni < 2; ++ni) {
        acc[mi][ni] = __builtin_amdgcn_mfma_f32_16x16x32_bf16(
            a[mi], bhf[ni], acc[mi][ni], 0, 0, 0);
        acc[mi][ni] = __builtin_amdgcn_mfma_f32_16x16x32_bf16(
            a[mi], blf[ni], acc[mi][ni], 0, 0, 0);
      }
    __syncthreads();
  }

  const int crowbase = qt * 128 + wr * 64 + ((lane >> 4) << 2);
  const int ccolbase = h * 64 + wc * 32 + (lane & 15);
#pragma unroll
  for (int ni = 0; ni < 2; ++ni) {
    const int col = ccolbase + ni * 16;
#pragma unroll
    for (int mi = 0; mi < 4; ++mi) {
      const int row0 = b * SEQ + crowbase + mi * 16;
#pragma unroll
      for (int j = 0; j < 4; ++j) {
        const float v = acc[mi][ni][j];
        const ushort hi = f2bf(v);
        ctxHi[(size_t)(row0 + j) * D_MODEL + col] = hi;
        ctxLo[(size_t)(row0 + j) * D_MODEL + col] = f2bf(v - bf2f(hi));
      }
    }
  }
}

// ---------------------------------------------------------------------------
extern "C" void kernel_launch(void* const* d_in, const int* in_sizes, int n_in,
                              void* d_out, int out_size, void* d_ws,
                              size_t ws_size, hipStream_t stream) {
  const float* queries = (const float*)d_in[0];
  const float* keys = (const float*)d_in[1];
  const float* values = (const float*)d_in[2];
  const float* W_Q = (const float*)d_in[3];
  const float* b_Q = (const float*)d_in[4];
  const float* W_K = (const float*)d_in[5];
  const float* b_K = (const float*)d_in[6];
  const float* W_V = (const float*)d_in[7];
  const float* b_V = (const float*)d_in[8];
  const float* W_O = (const float*)d_in[9];
  const float* b_O = (const float*)d_in[10];

  float* out = (float*)d_out;                         // (B,S,D)
  float* attn = out + (size_t)BATCH * SEQ * D_MODEL;  // (B,H,S,S)

  const size_t PE = (size_t)M_PROJ * D_MODEL;  // 8388608
  const size_t D2 = (size_t)D_MODEL * D_MODEL;
  ushort* Xhi = (ushort*)d_ws;
  ushort* Xlo = Xhi + PE;
  ushort* Wthi = Xlo + PE;
  ushort* Wtlo = Wthi + D2;
  ushort* Qhi = Wtlo + D2;
  ushort* Qlo = Qhi + PE;
  ushort* Khi = Qlo + PE;
  ushort* Klo = Khi + PE;
  ushort* Vthi = Klo + PE;
  ushort* Vtlo = Vthi + PE;
  ushort* ctxHi = Vtlo + PE;
  ushort* ctxLo = ctxHi + PE;
  ushort* Phi = ctxLo + PE;  // (B,H,S,S) bf16 = 537 MB; ws ~4.4 GB per fills
  // total ws use ~= 709 MB

  const dim3 blk(256);
  const int n4 = (int)(PE / 4);
  const dim3 ggemm(512);

  // Q = queries @ W_Q + b_Q  -> bf16 hi/lo
  split_kernel<<<2048, blk, 0, stream>>>(queries, Xhi, Xlo, n4);
  transpose_split_kernel<<<dim3(16, 16), blk, 0, stream>>>(W_Q, Wthi, Wtlo);
  mfma_gemm_kernel<1><<<ggemm, blk, 0, stream>>>(
      Xhi, Xlo, Wthi, Wtlo, b_Q, nullptr, Qhi, Qlo, M_PROJ, D_MODEL, D_MODEL);

  // K
  split_kernel<<<2048, blk, 0, stream>>>(keys, Xhi, Xlo, n4);
  transpose_split_kernel<<<dim3(16, 16), blk, 0, stream>>>(W_K, Wthi, Wtlo);
  mfma_gemm_kernel<1><<<ggemm, blk, 0, stream>>>(
      Xhi, Xlo, Wthi, Wtlo, b_K, nullptr, Khi, Klo, M_PROJ, D_MODEL, D_MODEL);

  // V -> transposed per-head Vt hi/lo
  split_kernel<<<2048, blk, 0, stream>>>(values, Xhi, Xlo, n4);
  transpose_split_kernel<<<dim3(16, 16), blk, 0, stream>>>(W_V, Wthi, Wtlo);
  mfma_gemm_kernel<2><<<ggemm, blk, 0, stream>>>(
      Xhi, Xlo, Wthi, Wtlo, b_V, nullptr, Vthi, Vtlo, M_PROJ, D_MODEL, D_MODEL);

  const int ntri = (SEQ / 128) * (SEQ / 128 + 1) / 2;  // 136
  scores_mfma_kernel<<<dim3(ntri, BATCH * NUM_HEADS), blk, 0, stream>>>(
      Qhi, Qlo, Khi, Klo, attn);

  softmax_kernel<<<dim3(BATCH * NUM_HEADS * SEQ), blk, 0, stream>>>(attn, Phi);

  pv_mfma_kernel<<<dim3(SEQ / 128, BATCH * NUM_HEADS), blk, 0, stream>>>(
      Phi, Vthi, Vtlo, ctxHi, ctxLo);

  // out = ctx @ W_O + b_O (fp32 out)
  transpose_split_kernel<<<dim3(16, 16), blk, 0, stream>>>(W_O, Wthi, Wtlo);
  mfma_gemm_kernel<0><<<ggemm, blk, 0, stream>>>(
      ctxHi, ctxLo, Wthi, Wtlo, b_O, out, nullptr, nullptr, M_PROJ, D_MODEL,
      D_MODEL);
}